// Round 5
// baseline (245.477 us; speedup 1.0000x reference)
//
#include <hip/hip_runtime.h>

#define D 128
#define LDA 136   // bf16 elems per LDS row (+8 pad)

typedef __attribute__((ext_vector_type(8))) short bf16x8;
typedef __attribute__((ext_vector_type(4))) float f32x4;

static __device__ __forceinline__ unsigned short f2bf(float f) {
    unsigned u = __float_as_uint(f);
    unsigned r = 0x7fffu + ((u >> 16) & 1u);   // round-to-nearest-even
    return (unsigned short)((u + r) >> 16);
}
static __device__ __forceinline__ float bflo(unsigned u) { return __uint_as_float(u << 16); }
static __device__ __forceinline__ float bfhi(unsigned u) { return __uint_as_float(u & 0xffff0000u); }

// ---------------------------------------------------------------------------
// Stage 0a: W [k][n] fp32 -> Wt [n][k] bf16.
// ---------------------------------------------------------------------------
__global__ __launch_bounds__(256) void wt_kernel(
    const float* __restrict__ W, unsigned short* __restrict__ Wt)
{
    int idx = blockIdx.x * 256 + threadIdx.x;   // 0..16383
    int k = idx >> 7, n = idx & 127;
    Wt[n * 128 + k] = f2bf(W[idx]);
}

// ---------------------------------------------------------------------------
// Stage 0b: H fp32 -> bf16 (8 elems/thread, streaming).
// ---------------------------------------------------------------------------
__global__ __launch_bounds__(256) void h2bf_kernel(
    const float* __restrict__ H, unsigned* __restrict__ Hb, int total8)
{
    int i = blockIdx.x * 256 + threadIdx.x;
    if (i >= total8) return;
    const float4* h4 = (const float4*)H;
    float4 v0 = h4[i * 2], v1 = h4[i * 2 + 1];
    uint4 o;
    o.x = (unsigned)f2bf(v0.x) | ((unsigned)f2bf(v0.y) << 16);
    o.y = (unsigned)f2bf(v0.z) | ((unsigned)f2bf(v0.w) << 16);
    o.z = (unsigned)f2bf(v1.x) | ((unsigned)f2bf(v1.y) << 16);
    o.w = (unsigned)f2bf(v1.z) | ((unsigned)f2bf(v1.w) << 16);
    ((uint4*)Hb)[i] = o;
}

// ---------------------------------------------------------------------------
// Stage 1: histogram of edge destinations.
// ---------------------------------------------------------------------------
__global__ __launch_bounds__(256) void hist_kernel(
    const int* __restrict__ edst, int* __restrict__ counts, int E)
{
    int e = blockIdx.x * 256 + threadIdx.x;
    if (e < E) atomicAdd(&counts[edst[e]], 1);
}

// ---------------------------------------------------------------------------
// Stage 2a: per-tile (1024) block-inclusive scan -> offsets[i+1], tilesums.
// ---------------------------------------------------------------------------
__global__ __launch_bounds__(1024) void scan_tile_kernel(
    const int* __restrict__ counts, int* __restrict__ offsets,
    int* __restrict__ tilesums, int n)
{
    __shared__ int wsum[16];
    const int tid = threadIdx.x;
    const int lane = tid & 63, wv = tid >> 6;
    int i = blockIdx.x * 1024 + tid;
    int x = (i < n) ? counts[i] : 0;
#pragma unroll
    for (int off = 1; off < 64; off <<= 1) {
        int t = __shfl_up(x, off, 64);
        if (lane >= off) x += t;
    }
    if (lane == 63) wsum[wv] = x;
    __syncthreads();
    if (wv == 0 && lane < 16) {
        int s = wsum[lane];
#pragma unroll
        for (int off = 1; off < 16; off <<= 1) {
            int t = __shfl_up(s, off, 64);
            if (lane >= off) s += t;
        }
        wsum[lane] = s;
    }
    __syncthreads();
    int waveoff = (wv == 0) ? 0 : wsum[wv - 1];
    if (i < n) offsets[i + 1] = waveoff + x;
    if (tid == 0) tilesums[blockIdx.x] = wsum[15];
}

// ---------------------------------------------------------------------------
// Stage 2b: exclusive scan of tile sums in place (1 block).
// ---------------------------------------------------------------------------
__global__ __launch_bounds__(1024) void scan_sums_kernel(
    int* __restrict__ tilesums, int ntiles)
{
    __shared__ int wsum[16];
    const int tid = threadIdx.x;
    const int lane = tid & 63, wv = tid >> 6;
    int x0 = (tid < ntiles) ? tilesums[tid] : 0;
    int x = x0;
#pragma unroll
    for (int off = 1; off < 64; off <<= 1) {
        int t = __shfl_up(x, off, 64);
        if (lane >= off) x += t;
    }
    if (lane == 63) wsum[wv] = x;
    __syncthreads();
    if (wv == 0 && lane < 16) {
        int s = wsum[lane];
#pragma unroll
        for (int off = 1; off < 16; off <<= 1) {
            int t = __shfl_up(s, off, 64);
            if (lane >= off) s += t;
        }
        wsum[lane] = s;
    }
    __syncthreads();
    int waveoff = (wv == 0) ? 0 : wsum[wv - 1];
    if (tid < ntiles) tilesums[tid] = waveoff + x - x0;   // exclusive
}

// ---------------------------------------------------------------------------
// Stage 2c: add tile prefixes back; offsets[0] = 0.
// ---------------------------------------------------------------------------
__global__ __launch_bounds__(1024) void scan_fixup_kernel(
    int* __restrict__ offsets, const int* __restrict__ tilesums, int n)
{
    int i = blockIdx.x * 1024 + threadIdx.x;
    if (i < n) offsets[i + 1] += tilesums[blockIdx.x];
    if (i == 0) offsets[0] = 0;
}

// ---------------------------------------------------------------------------
// Stage 3: counting-sort scatter. counts doubles as down-cursor (-> 0),
// so no separate cursors array / memset.
// ---------------------------------------------------------------------------
__global__ __launch_bounds__(256) void sort_kernel(
    const int* __restrict__ esrc, const int* __restrict__ edst,
    const int* __restrict__ offsets, int* __restrict__ counts,
    int* __restrict__ sorted_src, int E)
{
    int e = blockIdx.x * 256 + threadIdx.x;
    if (e < E) {
        int d = edst[e];
        int c = atomicAdd(&counts[d], -1);          // pre-value: deg..1
        sorted_src[offsets[d] + c - 1] = esrc[e];
    }
}

// ---------------------------------------------------------------------------
// Stage 4 (fused): per block of 64 dst rows — each wave aggregates 16 rows
// directly into the LDS A-tile (bf16), then bf16 MFMA GEMM + deg/bias/relu
// epilogue. d_out is write-once. BF16H: gather from pre-converted bf16 H
// (16 lanes/edge x 16B, 4 edges concurrent); else fp32 H (32 lanes/edge,
// 2 edges concurrent).
// ---------------------------------------------------------------------------
template<bool BF16H>
__global__ __launch_bounds__(256) void agg_gemm_kernel(
    const float* __restrict__ H, const uint4* __restrict__ Hb,
    const int* __restrict__ sorted_src, const int* __restrict__ offsets,
    const unsigned short* __restrict__ Wt, const float* __restrict__ b,
    float* __restrict__ out, int n_dst)
{
    __shared__ __align__(16) unsigned char smem[52224];
    unsigned short* Ash = (unsigned short*)smem;                   // [64][LDA]
    unsigned short* Wsh = (unsigned short*)(smem + 64 * LDA * 2);  // [128][LDA]
    float* Csh = (float*)smem;                                     // [64][132]

    const int tid  = threadIdx.x;
    const int lane = tid & 63, wv = tid >> 6;
    const size_t row0 = (size_t)blockIdx.x * 64;

    // Stage Wt: 128x128 bf16 (coalesced uint4).
#pragma unroll
    for (int t = 0; t < 8; ++t) {
        int i = tid + t * 256;
        int n = i >> 4, k8 = (i & 15) << 3;
        *(uint4*)&Wsh[n * LDA + k8] = ((const uint4*)Wt)[i];
    }

    // Aggregate 16 rows per wave into Ash (bf16).
    const int quad = lane >> 4, ql = lane & 15;   // bf16 path
    const int half = lane >> 5, hl = lane & 31;   // fp32 path
    for (int r = 0; r < 16; ++r) {
        size_t grow = row0 + (size_t)wv * 16 + r;
        int beg = 0, end = 0;
        if (grow < (size_t)n_dst) { beg = offsets[grow]; end = offsets[grow + 1]; }
        if (BF16H) {
            float acc[8] = {0, 0, 0, 0, 0, 0, 0, 0};
            for (int chunk = beg; chunk < end; chunk += 64) {
                int m = end - chunk; if (m > 64) m = 64;
                int idx = (lane < m) ? sorted_src[chunk + lane] : 0;
                for (int j = 0; j < m; j += 4) {
                    int jj = j + quad;
                    int s = __shfl(idx, jj < m ? jj : m - 1);
                    uint4 hv = Hb[(size_t)s * 16 + ql];
                    float w = (jj < m) ? 1.f : 0.f;
                    acc[0] += w * bflo(hv.x); acc[1] += w * bfhi(hv.x);
                    acc[2] += w * bflo(hv.y); acc[3] += w * bfhi(hv.y);
                    acc[4] += w * bflo(hv.z); acc[5] += w * bfhi(hv.z);
                    acc[6] += w * bflo(hv.w); acc[7] += w * bfhi(hv.w);
                }
            }
#pragma unroll
            for (int k = 0; k < 8; ++k) {
                acc[k] += __shfl_xor(acc[k], 16);
                acc[k] += __shfl_xor(acc[k], 32);
            }
            if (quad == 0) {
                uint4 o;
                o.x = (unsigned)f2bf(acc[0]) | ((unsigned)f2bf(acc[1]) << 16);
                o.y = (unsigned)f2bf(acc[2]) | ((unsigned)f2bf(acc[3]) << 16);
                o.z = (unsigned)f2bf(acc[4]) | ((unsigned)f2bf(acc[5]) << 16);
                o.w = (unsigned)f2bf(acc[6]) | ((unsigned)f2bf(acc[7]) << 16);
                *(uint4*)&Ash[(wv * 16 + r) * LDA + ql * 8] = o;
            }
        } else {
            float acc[4] = {0, 0, 0, 0};
            const float4* H4 = (const float4*)H;
            for (int chunk = beg; chunk < end; chunk += 64) {
                int m = end - chunk; if (m > 64) m = 64;
                int idx = (lane < m) ? sorted_src[chunk + lane] : 0;
                for (int j = 0; j < m; j += 2) {
                    int jj = j + half;
                    int s = __shfl(idx, jj < m ? jj : m - 1);
                    float4 v = H4[(size_t)s * 32 + hl];
                    float w = (jj < m) ? 1.f : 0.f;
                    acc[0] += w * v.x; acc[1] += w * v.y;
                    acc[2] += w * v.z; acc[3] += w * v.w;
                }
            }
#pragma unroll
            for (int k = 0; k < 4; ++k) acc[k] += __shfl_xor(acc[k], 32);
            if (half == 0) {
                uint2 o;
                o.x = (unsigned)f2bf(acc[0]) | ((unsigned)f2bf(acc[1]) << 16);
                o.y = (unsigned)f2bf(acc[2]) | ((unsigned)f2bf(acc[3]) << 16);
                *(uint2*)&Ash[(wv * 16 + r) * LDA + hl * 4] = o;
            }
        }
    }
    __syncthreads();

    // MFMA: wave wv owns rows [16wv,16wv+16) x 128 cols.
    const int m0 = wv * 16;
    const int fl = lane & 15;

    f32x4 cacc[8];
#pragma unroll
    for (int n = 0; n < 8; ++n) cacc[n] = (f32x4){0.f, 0.f, 0.f, 0.f};

#pragma unroll
    for (int kc = 0; kc < 128; kc += 32) {
        bf16x8 a = *(const bf16x8*)&Ash[(m0 + fl) * LDA + kc + quad * 8];
#pragma unroll
        for (int n = 0; n < 8; ++n) {
            bf16x8 bf = *(const bf16x8*)&Wsh[(n * 16 + fl) * LDA + kc + quad * 8];
            cacc[n] = __builtin_amdgcn_mfma_f32_16x16x32_bf16(a, bf, cacc[n], 0, 0, 0);
        }
    }

    // Per-lane degree info for its 4 C rows (row = quad*4 + r).
    float inv[4], gate[4];
#pragma unroll
    for (int r = 0; r < 4; ++r) {
        size_t gr = row0 + m0 + quad * 4 + r;
        int dg = (gr < (size_t)n_dst) ? offsets[gr + 1] - offsets[gr] : 0;
        inv[r]  = 1.0f / (float)(dg > 1 ? dg : 1);
        gate[r] = (dg > 0) ? 1.0f : 0.0f;
    }
    __syncthreads();   // Ash/Wsh dead; reuse as Csh

#pragma unroll
    for (int n = 0; n < 8; ++n) {
        int col = n * 16 + fl;
        float bc = b[col];
#pragma unroll
        for (int r = 0; r < 4; ++r) {
            float v = cacc[n][r] * inv[r] + bc * gate[r];
            Csh[(m0 + quad * 4 + r) * 132 + col] = fmaxf(v, 0.0f);
        }
    }
    __syncthreads();

    // Coalesced float4 store (write-once to out).
#pragma unroll
    for (int t = 0; t < 8; ++t) {
        int i = tid + t * 256;
        int rr = i >> 5, c4 = i & 31;
        size_t gr = row0 + rr;
        if (gr < (size_t)n_dst)
            ((float4*)out)[gr * (D / 4) + c4] = *(float4*)&Csh[rr * 132 + c4 * 4];
    }
}

extern "C" void kernel_launch(void* const* d_in, const int* in_sizes, int n_in,
                              void* d_out, int out_size, void* d_ws, size_t ws_size,
                              hipStream_t stream) {
    const float* H    = (const float*)d_in[0];   // [N_src, 128]
    const float* W    = (const float*)d_in[1];   // [128, 128]
    const float* b    = (const float*)d_in[2];   // [128]
    const int*   esrc = (const int*)d_in[3];     // [E]
    const int*   edst = (const int*)d_in[4];     // [E]
    const int    E     = in_sizes[3];
    const int    n_dst = out_size / D;
    const int    nsrc_elems = in_sizes[0];       // N_src * 128
    const int    ntiles = (n_dst + 1023) / 1024;

    float* out = (float*)d_out;

    // ws layout: [Wt 32KB][counts n][offsets n+1][tilesums][sorted E][Hb (opt)]
    char* p = (char*)d_ws;
    unsigned short* Wt = (unsigned short*)p;  p += 128 * 128 * sizeof(unsigned short);
    int* counts   = (int*)p;  p += (size_t)n_dst * 4;
    int* offsets  = (int*)p;  p += ((size_t)n_dst + 1) * 4;
    int* tilesums = (int*)p;  p += (size_t)ntiles * 4;
    int* sorted   = (int*)p;  p += (size_t)E * 4;
    size_t hb_off = (((size_t)(p - (char*)d_ws)) + 255) & ~(size_t)255;
    bool use_bf16h = (ws_size >= hb_off + (size_t)nsrc_elems * 2);
    unsigned* Hb = (unsigned*)((char*)d_ws + hb_off);

    hipMemsetAsync(counts, 0, (size_t)n_dst * sizeof(int), stream);

    wt_kernel<<<64, 256, 0, stream>>>(W, Wt);
    if (use_bf16h)
        h2bf_kernel<<<(nsrc_elems / 8 + 255) / 256, 256, 0, stream>>>(H, Hb, nsrc_elems / 8);
    hist_kernel<<<(E + 255) / 256, 256, 0, stream>>>(edst, counts, E);
    scan_tile_kernel<<<ntiles, 1024, 0, stream>>>(counts, offsets, tilesums, n_dst);
    scan_sums_kernel<<<1, 1024, 0, stream>>>(tilesums, ntiles);
    scan_fixup_kernel<<<ntiles, 1024, 0, stream>>>(offsets, tilesums, n_dst);
    sort_kernel<<<(E + 255) / 256, 256, 0, stream>>>(esrc, edst, offsets, counts, sorted, E);

    const int nblk = (n_dst + 63) / 64;
    if (use_bf16h)
        agg_gemm_kernel<true><<<nblk, 256, 0, stream>>>(
            H, (const uint4*)Hb, sorted, offsets, Wt, b, out, n_dst);
    else
        agg_gemm_kernel<false><<<nblk, 256, 0, stream>>>(
            H, nullptr, sorted, offsets, Wt, b, out, n_dst);
}

// Round 6
// 208.929 us; speedup vs baseline: 1.1749x; 1.1749x over previous
//
#include <hip/hip_runtime.h>

#define D 128
#define LDA 136   // bf16 elems per LDS row (+8 pad)

typedef __attribute__((ext_vector_type(8))) short bf16x8;
typedef __attribute__((ext_vector_type(4))) float f32x4;

static __device__ __forceinline__ unsigned short f2bf(float f) {
    unsigned u = __float_as_uint(f);
    unsigned r = 0x7fffu + ((u >> 16) & 1u);   // round-to-nearest-even
    return (unsigned short)((u + r) >> 16);
}
static __device__ __forceinline__ float bflo(unsigned u) { return __uint_as_float(u << 16); }
static __device__ __forceinline__ float bfhi(unsigned u) { return __uint_as_float(u & 0xffff0000u); }

// ---------------------------------------------------------------------------
// Stage 0 (merged init): [0,nh8) H fp32->bf16 (uint4 units); [nh8,+16384) W
// transpose->bf16; then zero counts; last slot zeroes the alloc cursor.
// ---------------------------------------------------------------------------
__global__ __launch_bounds__(256) void init_kernel(
    const float* __restrict__ H, unsigned* __restrict__ Hb, int nh8,
    const float* __restrict__ W, unsigned short* __restrict__ Wt,
    int* __restrict__ counts, int n_dst, int* __restrict__ total)
{
    int i = blockIdx.x * 256 + threadIdx.x;
    if (i < nh8) {
        const float4* h4 = (const float4*)H;
        float4 v0 = h4[(size_t)i * 2], v1 = h4[(size_t)i * 2 + 1];
        uint4 o;
        o.x = (unsigned)f2bf(v0.x) | ((unsigned)f2bf(v0.y) << 16);
        o.y = (unsigned)f2bf(v0.z) | ((unsigned)f2bf(v0.w) << 16);
        o.z = (unsigned)f2bf(v1.x) | ((unsigned)f2bf(v1.y) << 16);
        o.w = (unsigned)f2bf(v1.z) | ((unsigned)f2bf(v1.w) << 16);
        ((uint4*)Hb)[i] = o;
        return;
    }
    int j = i - nh8;
    if (j < 16384) {                       // Wt[n][k] = bf16(W[k][n])
        int k = j >> 7, n = j & 127;
        Wt[n * 128 + k] = f2bf(W[j]);
        return;
    }
    j -= 16384;
    if (j < n_dst) { counts[j] = 0; return; }
    if (j == n_dst) *total = 0;
}

// ---------------------------------------------------------------------------
// Stage 1: histogram of edge destinations.
// ---------------------------------------------------------------------------
__global__ __launch_bounds__(256) void hist_kernel(
    const int* __restrict__ edst, int* __restrict__ counts, int E)
{
    int e = blockIdx.x * 256 + threadIdx.x;
    if (e < E) atomicAdd(&counts[edst[e]], 1);
}

// ---------------------------------------------------------------------------
// Stage 2: segment allocation WITHOUT a scan. Order of segments is
// irrelevant for a sum, so each wave prefix-sums 64 counts and grabs a base
// with ONE atomicAdd on a global cursor (~782 atomics total).
// Saves deg[] for the epilogue (counts gets consumed by sort).
// ---------------------------------------------------------------------------
__global__ __launch_bounds__(256) void alloc_kernel(
    const int* __restrict__ counts, int* __restrict__ beg,
    int* __restrict__ deg, int* __restrict__ total, int n)
{
    int i = blockIdx.x * 256 + threadIdx.x;
    int lane = threadIdx.x & 63;
    int c = (i < n) ? counts[i] : 0;
    int x = c;
#pragma unroll
    for (int off = 1; off < 64; off <<= 1) {
        int t = __shfl_up(x, off, 64);
        if (lane >= off) x += t;
    }
    int base = 0;
    if (lane == 63) base = atomicAdd(total, x);   // x = wave total at lane 63
    base = __shfl(base, 63, 64);
    if (i < n) { beg[i] = base + x - c; deg[i] = c; }
}

// ---------------------------------------------------------------------------
// Stage 3: counting-sort scatter; counts doubles as down-cursor (deg -> 0).
// ---------------------------------------------------------------------------
__global__ __launch_bounds__(256) void sort_kernel(
    const int* __restrict__ esrc, const int* __restrict__ edst,
    const int* __restrict__ beg, int* __restrict__ counts,
    int* __restrict__ sorted_src, int E)
{
    int e = blockIdx.x * 256 + threadIdx.x;
    if (e < E) {
        int d = edst[e];
        int c = atomicAdd(&counts[d], -1);        // pre-value: deg..1
        sorted_src[beg[d] + c - 1] = esrc[e];
    }
}

// ---------------------------------------------------------------------------
// Stage 4: pull aggregation, standalone (no LDS -> high occupancy for
// latency hiding; round-5 lesson). One wave per dst row. BF16H: 16 lanes x
// 16B per H row, 4 edges concurrent. Output agg in bf16 (halves the
// agg->gemm round-trip).
// ---------------------------------------------------------------------------
template<bool BF16H>
__global__ __launch_bounds__(256) void aggregate_kernel(
    const float* __restrict__ H, const uint4* __restrict__ Hb,
    const int* __restrict__ sorted_src, const int* __restrict__ beg,
    const int* __restrict__ deg, unsigned short* __restrict__ aggb, int n_dst)
{
    int dst = blockIdx.x * 4 + (threadIdx.x >> 6);
    if (dst >= n_dst) return;
    int lane = threadIdx.x & 63;
    int b0 = beg[dst], e0 = b0 + deg[dst];

    if (BF16H) {
        const int ql = lane & 15, quad = lane >> 4;
        float acc[8] = {0, 0, 0, 0, 0, 0, 0, 0};
        for (int chunk = b0; chunk < e0; chunk += 64) {
            int m = e0 - chunk; if (m > 64) m = 64;
            int idx = (lane < m) ? sorted_src[chunk + lane] : 0;
            for (int j = 0; j < m; j += 4) {
                int jj = j + quad;
                int s = __shfl(idx, jj < m ? jj : m - 1);
                uint4 hv = Hb[(size_t)s * 16 + ql];
                float w = (jj < m) ? 1.f : 0.f;
                acc[0] += w * bflo(hv.x); acc[1] += w * bfhi(hv.x);
                acc[2] += w * bflo(hv.y); acc[3] += w * bfhi(hv.y);
                acc[4] += w * bflo(hv.z); acc[5] += w * bfhi(hv.z);
                acc[6] += w * bflo(hv.w); acc[7] += w * bfhi(hv.w);
            }
        }
#pragma unroll
        for (int k = 0; k < 8; ++k) {
            acc[k] += __shfl_xor(acc[k], 16);
            acc[k] += __shfl_xor(acc[k], 32);
        }
        if (quad == 0) {
            uint4 o;
            o.x = (unsigned)f2bf(acc[0]) | ((unsigned)f2bf(acc[1]) << 16);
            o.y = (unsigned)f2bf(acc[2]) | ((unsigned)f2bf(acc[3]) << 16);
            o.z = (unsigned)f2bf(acc[4]) | ((unsigned)f2bf(acc[5]) << 16);
            o.w = (unsigned)f2bf(acc[6]) | ((unsigned)f2bf(acc[7]) << 16);
            ((uint4*)aggb)[(size_t)dst * 16 + ql] = o;
        }
    } else {
        const int hl = lane & 31, half = lane >> 5;
        float acc[4] = {0, 0, 0, 0};
        const float4* H4 = (const float4*)H;
        for (int chunk = b0; chunk < e0; chunk += 64) {
            int m = e0 - chunk; if (m > 64) m = 64;
            int idx = (lane < m) ? sorted_src[chunk + lane] : 0;
            for (int j = 0; j < m; j += 2) {
                int jj = j + half;
                int s = __shfl(idx, jj < m ? jj : m - 1);
                float4 v = H4[(size_t)s * 32 + hl];
                float w = (jj < m) ? 1.f : 0.f;
                acc[0] += w * v.x; acc[1] += w * v.y;
                acc[2] += w * v.z; acc[3] += w * v.w;
            }
        }
#pragma unroll
        for (int k = 0; k < 4; ++k) acc[k] += __shfl_xor(acc[k], 32);
        if (half == 0) {
            uint2 o;
            o.x = (unsigned)f2bf(acc[0]) | ((unsigned)f2bf(acc[1]) << 16);
            o.y = (unsigned)f2bf(acc[2]) | ((unsigned)f2bf(acc[3]) << 16);
            ((uint2*)aggb)[(size_t)dst * 32 + hl] = o;
        }
    }
}

// ---------------------------------------------------------------------------
// Stage 5: out = relu( (aggb @ W) / max(deg,1) + (deg>0 ? b : 0) ) via bf16
// MFMA. A staged from bf16 aggb (straight uint4 copy). Write-once to d_out.
// ---------------------------------------------------------------------------
__global__ __launch_bounds__(256) void gemm_finalize_kernel(
    const unsigned short* __restrict__ aggb, const unsigned short* __restrict__ Wt,
    const float* __restrict__ b, const int* __restrict__ deg,
    float* __restrict__ out, int n_dst)
{
    __shared__ __align__(16) unsigned char smem[52224];
    unsigned short* Ash = (unsigned short*)smem;                   // [64][LDA]
    unsigned short* Wsh = (unsigned short*)(smem + 64 * LDA * 2);  // [128][LDA]
    float* Csh = (float*)smem;                                     // [64][132]

    const int tid  = threadIdx.x;
    const int lane = tid & 63, wv = tid >> 6;
    const size_t row0 = (size_t)blockIdx.x * 64;

    // Stage A: 64 rows x 16 uint4 (bf16, coalesced copy).
#pragma unroll
    for (int t = 0; t < 4; ++t) {
        int i = tid + t * 256;
        int r = i >> 4, k8 = (i & 15) << 3;
        size_t gr = row0 + r;
        uint4 v = (gr < (size_t)n_dst) ? ((const uint4*)aggb)[gr * 16 + (i & 15)]
                                       : make_uint4(0, 0, 0, 0);
        *(uint4*)&Ash[r * LDA + k8] = v;
    }
    // Stage Wt: 128 x 16 uint4.
#pragma unroll
    for (int t = 0; t < 8; ++t) {
        int i = tid + t * 256;
        int n = i >> 4, k8 = (i & 15) << 3;
        *(uint4*)&Wsh[n * LDA + k8] = ((const uint4*)Wt)[i];
    }
    __syncthreads();

    const int m0 = wv * 16;
    const int fl = lane & 15, quad = lane >> 4;

    f32x4 cacc[8];
#pragma unroll
    for (int n = 0; n < 8; ++n) cacc[n] = (f32x4){0.f, 0.f, 0.f, 0.f};

#pragma unroll
    for (int kc = 0; kc < 128; kc += 32) {
        bf16x8 a = *(const bf16x8*)&Ash[(m0 + fl) * LDA + kc + quad * 8];
#pragma unroll
        for (int n = 0; n < 8; ++n) {
            bf16x8 bf = *(const bf16x8*)&Wsh[(n * 16 + fl) * LDA + kc + quad * 8];
            cacc[n] = __builtin_amdgcn_mfma_f32_16x16x32_bf16(a, bf, cacc[n], 0, 0, 0);
        }
    }

    float inv[4], gate[4];
#pragma unroll
    for (int r = 0; r < 4; ++r) {
        size_t gr = row0 + m0 + quad * 4 + r;
        int dg = (gr < (size_t)n_dst) ? deg[gr] : 0;
        inv[r]  = 1.0f / (float)(dg > 1 ? dg : 1);
        gate[r] = (dg > 0) ? 1.0f : 0.0f;
    }
    __syncthreads();   // Ash/Wsh dead; reuse as Csh

#pragma unroll
    for (int n = 0; n < 8; ++n) {
        int col = n * 16 + fl;
        float bc = b[col];
#pragma unroll
        for (int r = 0; r < 4; ++r) {
            float v = cacc[n][r] * inv[r] + bc * gate[r];
            Csh[(m0 + quad * 4 + r) * 132 + col] = fmaxf(v, 0.0f);
        }
    }
    __syncthreads();

#pragma unroll
    for (int t = 0; t < 8; ++t) {
        int i = tid + t * 256;
        int rr = i >> 5, c4 = i & 31;
        size_t gr = row0 + rr;
        if (gr < (size_t)n_dst)
            ((float4*)out)[gr * (D / 4) + c4] = *(float4*)&Csh[rr * 132 + c4 * 4];
    }
}

extern "C" void kernel_launch(void* const* d_in, const int* in_sizes, int n_in,
                              void* d_out, int out_size, void* d_ws, size_t ws_size,
                              hipStream_t stream) {
    const float* H    = (const float*)d_in[0];   // [N_src, 128]
    const float* W    = (const float*)d_in[1];   // [128, 128]
    const float* b    = (const float*)d_in[2];   // [128]
    const int*   esrc = (const int*)d_in[3];     // [E]
    const int*   edst = (const int*)d_in[4];     // [E]
    const int    E     = in_sizes[3];
    const int    n_dst = out_size / D;
    const int    nsrc_elems = in_sizes[0];       // N_src * 128

    float* out = (float*)d_out;

    // ws: Wt | counts | beg | deg | total | sorted | aggb(align) | Hb(align)
    char* p = (char*)d_ws;
    unsigned short* Wt = (unsigned short*)p;  p += 128 * 128 * sizeof(unsigned short);
    int* counts = (int*)p;  p += (size_t)n_dst * 4;
    int* beg    = (int*)p;  p += (size_t)n_dst * 4;
    int* deg    = (int*)p;  p += (size_t)n_dst * 4;
    int* total  = (int*)p;  p += 256;            // padded for alignment
    int* sorted = (int*)p;  p += (size_t)E * 4;
    size_t agg_off = (((size_t)(p - (char*)d_ws)) + 255) & ~(size_t)255;
    unsigned short* aggb = (unsigned short*)((char*)d_ws + agg_off);
    size_t hb_off = (agg_off + (size_t)n_dst * D * 2 + 255) & ~(size_t)255;
    bool use_bf16h = (ws_size >= hb_off + (size_t)nsrc_elems * 2);
    unsigned* Hb = (unsigned*)((char*)d_ws + hb_off);

    const int nh8 = use_bf16h ? nsrc_elems / 8 : 0;
    const int init_work = nh8 + 16384 + n_dst + 1;

    init_kernel<<<(init_work + 255) / 256, 256, 0, stream>>>(
        H, Hb, nh8, W, Wt, counts, n_dst, total);
    hist_kernel<<<(E + 255) / 256, 256, 0, stream>>>(edst, counts, E);
    alloc_kernel<<<(n_dst + 255) / 256, 256, 0, stream>>>(counts, beg, deg, total, n_dst);
    sort_kernel<<<(E + 255) / 256, 256, 0, stream>>>(esrc, edst, beg, counts, sorted, E);

    const int nblk_agg = (n_dst + 3) / 4;
    if (use_bf16h)
        aggregate_kernel<true><<<nblk_agg, 256, 0, stream>>>(
            H, (const uint4*)Hb, sorted, beg, deg, aggb, n_dst);
    else
        aggregate_kernel<false><<<nblk_agg, 256, 0, stream>>>(
            H, nullptr, sorted, beg, deg, aggb, n_dst);

    gemm_finalize_kernel<<<(n_dst + 63) / 64, 256, 0, stream>>>(
        aggb, Wt, b, deg, out, n_dst);
}